// Round 6
// baseline (526.816 us; speedup 1.0000x reference)
//
#include <hip/hip_runtime.h>

// Gemma2 attention, S=4096 HID=2048 NH=8 NKV=4 HD=256, causal, tanh softcap 50,
// scaling 1/16. R11: flash rebuilt as ONE 8-wave block/CU with QBLK=128 and
// double-buffered K/V (144KB LDS). Halves staging bytes per MFMA (33 tiles x
// 64KB/CU vs R9's 65) and hides stage latency via full-tile-flight prefetch
// (R7b schedule: lgkm-only P-barrier, vmcnt-transparent; validated R2 bench).
// Balance: pair (j, 31-j) -> 66 k-tiles split 33/33 via additive partials
// (softcap exp has no running max): A = qtile j full + qtile(31-j) k[0,31-2j);
// B = qtile(31-j) k[31-2j,64-2j) incl diagonal. combine = (PA+PB)/(lA+lB).
// grid 256 = 1 block/CU, 2 waves/SIMD. Also: rope computes sincos once per
// (s,i) and loops 12 heads (was 12x redundant transcendentals).

#define SEQ 4096
#define HIDDEN 2048
#define NHEADS 8
#define HDIM 256

typedef unsigned short u16;
typedef __attribute__((ext_vector_type(8))) __bf16 bf16x8;
typedef __attribute__((ext_vector_type(4))) float f32x4;
typedef __attribute__((ext_vector_type(16))) float f32x16;

static __device__ inline u16 f2bf(float f) {
  union { float f; unsigned u; } x; x.f = f;
  unsigned r = x.u + 0x7FFFu + ((x.u >> 16) & 1u);   // RNE
  return (u16)(r >> 16);
}
static __device__ inline float bf2f(u16 u) {
  union { unsigned u; float f; } x; x.u = ((unsigned)u) << 16;
  return x.f;
}

typedef __attribute__((address_space(1))) const unsigned int* gp_t;
typedef __attribute__((address_space(3))) unsigned int* lp_t;
static __device__ inline void load_lds16(const u16* g, u16* l) {
  __builtin_amdgcn_global_load_lds((gp_t)g, (lp_t)l, 16, 0, 0);
}

#define BARX() do { __builtin_amdgcn_s_barrier(); asm volatile("" ::: "memory"); } while (0)

// ---------------- prep kernels ----------------

__global__ void convert_hs_kernel(const float* __restrict__ src, u16* __restrict__ dst) {
  int i = blockIdx.x * 256 + threadIdx.x;
  float4 v = ((const float4*)src)[i];
  ushort4 o;
  o.x = f2bf(v.x); o.y = f2bf(v.y); o.z = f2bf(v.z); o.w = f2bf(v.w);
  ((ushort4*)dst)[i] = o;
}

// src fp32 (K x N) -> dst bf16 (N x K), dst row stride = K (HIDDEN)
__global__ void transpose_w_kernel(const float* __restrict__ src, u16* __restrict__ dst,
                                   int K, int N) {
  __shared__ u16 tile[64][65];
  int n0 = blockIdx.x * 64, k0 = blockIdx.y * 64;
  int tid = threadIdx.x;
  for (int i = 0; i < 16; i++) {
    int idx = i * 256 + tid; int r = idx >> 6, c = idx & 63;
    tile[r][c] = f2bf(src[(size_t)(k0 + r) * N + n0 + c]);
  }
  __syncthreads();
  for (int i = 0; i < 16; i++) {
    int idx = i * 256 + tid; int r = idx >> 6, c = idx & 63;
    dst[(size_t)(n0 + r) * K + k0 + c] = tile[c][r];
  }
}

// RoPE in place on qkv[4096][4096]: q cols 0..2047, k cols 2048..3071.
// One sincos per (s,i); loop the 12 q/k "heads" (12x fewer transcendentals).
__global__ void rope_kernel(u16* qkv) {
  int idx = blockIdx.x * 256 + threadIdx.x;        // 4096*128
  int s = idx >> 7;
  int i = idx & 127;
  float inv = __expf(-(float)i * 0.0719557841560639f);  // ln(10000)/128
  float ang = (float)s * inv;
  float sn, cs;
  sincosf(ang, &sn, &cs);
  size_t rowb = (size_t)s * 4096;
#pragma unroll
  for (int hh = 0; hh < 12; hh++) {
    size_t base = rowb + hh * 256 + i;
    float a = bf2f(qkv[base]);
    float b = bf2f(qkv[base + 128]);
    qkv[base]       = f2bf(a * cs - b * sn);
    qkv[base + 128] = f2bf(b * cs + a * sn);
  }
}

// qkv v-part (rows s, cols 3072+d), d in 0..1023 -> vT[d][s]
__global__ void transpose_v_kernel(const u16* __restrict__ qkv, u16* __restrict__ vT) {
  __shared__ u16 tile[64][65];
  int d0 = blockIdx.x * 64, s0 = blockIdx.y * 64;
  int tid = threadIdx.x;
  for (int i = 0; i < 16; i++) {
    int idx = i * 256 + tid; int r = idx >> 6, c = idx & 63;
    tile[r][c] = qkv[(size_t)(s0 + r) * 4096 + 3072 + d0 + c];
  }
  __syncthreads();
  for (int i = 0; i < 16; i++) {
    int idx = i * 256 + tid; int r = idx >> 6, c = idx & 63;
    vT[(size_t)(d0 + r) * 4096 + s0 + c] = tile[c][r];
  }
}

// ---------------- GEMM 256^2, BK=32, ring-4, counted vmcnt (gemm1) ----------------

__global__ __launch_bounds__(512, 2) void gemm256_kernel(
    const u16* __restrict__ A, const u16* __restrict__ Bt, u16* __restrict__ C,
    int M, int N, int K) {
  __shared__ __attribute__((aligned(16))) u16 lds[4][2][256 * 32];
  int tid = threadIdx.x;
  int wid = tid >> 6, lane = tid & 63;
  int lm = lane & 15, kq = lane >> 4;
  int wm = (wid >> 2) * 128, wn = (wid & 3) * 64;
  int m0 = blockIdx.y * 256, n0 = blockIdx.x * 256;
  int T = K >> 5;

  int idx0 = tid, idx1 = 512 + tid;
  int r0 = idx0 >> 2, c0 = idx0 & 3;
  int r1 = idx1 >> 2, c1 = idx1 & 3;
  const u16* gA0 = A  + (size_t)(m0 + r0) * K + ((c0 ^ (r0 & 3)) << 3);
  const u16* gA1 = A  + (size_t)(m0 + r1) * K + ((c1 ^ (r1 & 3)) << 3);
  const u16* gB0 = Bt + (size_t)(n0 + r0) * K + ((c0 ^ (r0 & 3)) << 3);
  const u16* gB1 = Bt + (size_t)(n0 + r1) * K + ((c1 ^ (r1 & 3)) << 3);

  f32x4 acc[8][4];
#pragma unroll
  for (int a = 0; a < 8; a++)
#pragma unroll
    for (int b = 0; b < 4; b++) acc[a][b] = (f32x4){0.f, 0.f, 0.f, 0.f};

  int xsw = ((kq ^ (lm & 3)) << 3);

#pragma unroll
  for (int t = 0; t < 2; t++) {
    int s = t & 3;
    load_lds16(gA0 + t * 32, &lds[s][0][idx0 * 8]);
    load_lds16(gA1 + t * 32, &lds[s][0][idx1 * 8]);
    load_lds16(gB0 + t * 32, &lds[s][1][idx0 * 8]);
    load_lds16(gB1 + t * 32, &lds[s][1][idx1 * 8]);
  }
  asm volatile("s_waitcnt vmcnt(4)" ::: "memory");
  BARX();

  for (int t = 0; t < T; ++t) {
    const u16* As = &lds[t & 3][0][0];
    const u16* Bs = &lds[t & 3][1][0];
    int sn = (t + 2) & 3;
    bool st = (t + 2) < T;

    bf16x8 a0[4], bb[4];
#pragma unroll
    for (int f = 0; f < 4; f++)
      a0[f] = *(const bf16x8*)&As[(wm + f * 16 + lm) * 32 + xsw];
#pragma unroll
    for (int f = 0; f < 4; f++)
      bb[f] = *(const bf16x8*)&Bs[(wn + f * 16 + lm) * 32 + xsw];
    if (st) {
      load_lds16(gA0 + (t + 2) * 32, &lds[sn][0][idx0 * 8]);
      load_lds16(gA1 + (t + 2) * 32, &lds[sn][0][idx1 * 8]);
    }
    BARX();
    __builtin_amdgcn_s_setprio(1);
#pragma unroll
    for (int mi = 0; mi < 4; mi++)
#pragma unroll
      for (int ni = 0; ni < 4; ni++)
        acc[mi][ni] = __builtin_amdgcn_mfma_f32_16x16x32_bf16(a0[mi], bb[ni],
                                                             acc[mi][ni], 0, 0, 0);
    __builtin_amdgcn_s_setprio(0);

    bf16x8 a1[4];
#pragma unroll
    for (int f = 0; f < 4; f++)
      a1[f] = *(const bf16x8*)&As[(wm + 64 + f * 16 + lm) * 32 + xsw];
    if (st) {
      load_lds16(gB0 + (t + 2) * 32, &lds[sn][1][idx0 * 8]);
      load_lds16(gB1 + (t + 2) * 32, &lds[sn][1][idx1 * 8]);
    }
    BARX();
    __builtin_amdgcn_s_setprio(1);
#pragma unroll
    for (int mi = 0; mi < 4; mi++)
#pragma unroll
      for (int ni = 0; ni < 4; ni++)
        acc[4 + mi][ni] = __builtin_amdgcn_mfma_f32_16x16x32_bf16(a1[mi], bb[ni],
                                                                 acc[4 + mi][ni], 0, 0, 0);
    __builtin_amdgcn_s_setprio(0);

    if (t < T - 1) {
      if (st) asm volatile("s_waitcnt vmcnt(4)" ::: "memory");
      else    asm volatile("s_waitcnt vmcnt(0)" ::: "memory");
      BARX();
    }
  }

#pragma unroll
  for (int mi = 0; mi < 8; mi++) {
    int row = m0 + wm + mi * 16 + kq * 4;
#pragma unroll
    for (int ni = 0; ni < 4; ni++) {
      int col = n0 + wn + ni * 16 + lm;
#pragma unroll
      for (int r = 0; r < 4; r++)
        C[(size_t)(row + r) * N + col] = f2bf(acc[mi][ni][r]);
    }
  }
}

// ---------------- GEMM (m97 structure): C = A(MxK) * Bt(NxK)^T ----------------

template <bool OUT_F32>
__global__ __launch_bounds__(256, 2) void gemm_bf16_kernel(
    const u16* __restrict__ A, const u16* __restrict__ Bt, void* __restrict__ Cout,
    int M, int N, int K) {
  __shared__ __attribute__((aligned(16))) u16 As[128 * 64];
  __shared__ __attribute__((aligned(16))) u16 Bs[128 * 64];
  int tid = threadIdx.x;
  int wave = tid >> 6, lane = tid & 63;
  int lm = lane & 15, qd = lane >> 4;
  int m0 = blockIdx.y * 128, n0 = blockIdx.x * 128;
  int wm = (wave >> 1) * 64, wn = (wave & 1) * 64;

  f32x4 acc[4][4];
#pragma unroll
  for (int a = 0; a < 4; a++)
#pragma unroll
    for (int b = 0; b < 4; b++) acc[a][b] = (f32x4){0.f, 0.f, 0.f, 0.f};

  int srow = lane >> 3;
  int scol = (lane & 7) * 8;

  for (int kt = 0; kt < K; kt += 64) {
    __syncthreads();
#pragma unroll
    for (int t = 0; t < 4; t++) {
      int j = wave * 4 + t;
      int row = j * 8 + srow;
      load_lds16(A  + (size_t)(m0 + row) * K + kt + scol, As + j * 512);
      load_lds16(Bt + (size_t)(n0 + row) * K + kt + scol, Bs + j * 512);
    }
    __syncthreads();
#pragma unroll
    for (int kk = 0; kk < 2; kk++) {
      bf16x8 af[4], bfr[4];
#pragma unroll
      for (int mi = 0; mi < 4; mi++)
        af[mi] = *(const bf16x8*)&As[(wm + mi * 16 + lm) * 64 + kk * 32 + qd * 8];
#pragma unroll
      for (int ni = 0; ni < 4; ni++)
        bfr[ni] = *(const bf16x8*)&Bs[(wn + ni * 16 + lm) * 64 + kk * 32 + qd * 8];
#pragma unroll
      for (int mi = 0; mi < 4; mi++)
#pragma unroll
        for (int ni = 0; ni < 4; ni++)
          acc[mi][ni] = __builtin_amdgcn_mfma_f32_16x16x32_bf16(af[mi], bfr[ni],
                                                               acc[mi][ni], 0, 0, 0);
    }
  }
#pragma unroll
  for (int mi = 0; mi < 4; mi++) {
    int row = m0 + wm + mi * 16 + qd * 4;
#pragma unroll
    for (int ni = 0; ni < 4; ni++) {
      int col = n0 + wn + ni * 16 + lm;
#pragma unroll
      for (int r = 0; r < 4; r++) {
        float v = acc[mi][ni][r];
        if (OUT_F32) ((float*)Cout)[(size_t)(row + r) * N + col] = v;
        else         ((u16*)Cout)[(size_t)(row + r) * N + col] = f2bf(v);
      }
    }
  }
}

// ---------------- flash attention, QBLK=128, 8 waves, dbuf K/V ----------------
// Block b (0..255): p=b&127, h=p&7 (XCD pin), j=p>>3 (0..15).
//  A (b<128):  seg0 qt=j      k[0,2j+2)      mode0 (owned, direct store)
//              seg1 qt=31-j   k[0,31-2j)     mode1 -> PA
//  B (b>=128): seg  qt=31-j   k[31-2j,64-2j) mode2 -> PB  (incl. diagonal)
// Waves: qq=w>>1 (32-q quarter), kh/dhalf=w&1. LDS: Ks 2x32K + Vs 2x32K +
// Pl 16K = 144KB (1 block/CU, 2 waves/SIMD). Per tile: [syncthreads: drains
// tile-t stage] -> prefetch t+1 -> S(2 chains) -> softcap -> P [lgkm-only
// barrier, prefetch stays in flight] -> PV + l-ones.

__global__ __launch_bounds__(512, 2) void flash_kernel(
    const u16* __restrict__ qkv, const u16* __restrict__ vT,
    u16* __restrict__ attn, float* __restrict__ PA, float* __restrict__ PB,
    float* __restrict__ lbuf /* == (float*)qkv base */) {
  __shared__ __attribute__((aligned(16))) u16 Ks[2][64 * 256];
  __shared__ __attribute__((aligned(16))) u16 Vs[2][256 * 64];
  __shared__ __attribute__((aligned(16))) u16 Pl[128 * 64];
  u16* Qs = &Ks[0][0];                         // 64KB flat Q staging area

  int tid = threadIdx.x;
  int w = tid >> 6, lane = tid & 63;
  int l31 = lane & 31, hi = lane >> 5;
  int qq = w >> 1, kh = w & 1, dhalf = w & 1;

  int b = blockIdx.x;            // 0..255
  int isA = (b < 128);
  int p = b & 127;
  int h = p & 7;                 // one head per XCD; same for paired A/B
  int j = p >> 3;                // 0..15
  int kvh = h >> 1;
  int nseg = isA ? 2 : 1;

  int vlc = (lane & 7) ^ ((lane >> 3) & 7);
  int vro = lane >> 3;

  const u16* Kg  = qkv + 2048 + (size_t)kvh * 256;
  const u16* Vg0 = vT + (size_t)(kvh * 256) * 4096;

  bf16x8 ones;
#pragma unroll
  for (int e = 0; e < 8; e++) ones[e] = (__bf16)1.0f;

  for (int si = 0; si < nseg; si++) {
    int qt, k0, k1, mode;
    if (isA && si == 0) { qt = j;      k0 = 0;          k1 = 2 * j + 2;  mode = 0; }
    else if (isA)       { qt = 31 - j; k0 = 0;          k1 = 31 - 2 * j; mode = 1; }
    else                { qt = 31 - j; k0 = 31 - 2 * j; k1 = 64 - 2 * j; mode = 2; }

    __syncthreads();                           // prev segment readers done
    {  // stage Q (128x256) flat across Ks[0..1]
      const u16* Qg = qkv + (size_t)(qt * 128) * 4096 + h * 256;
#pragma unroll
      for (int s = 0; s < 8; s++) {
        int idx = w * 8 + s;                   // 0..63
        int kr = idx * 2 + hi;                 // 0..127
        int klc = l31 ^ (kr & 31);
        load_lds16(Qg + (size_t)kr * 4096 + klc * 8, Qs + idx * 512);
      }
    }
    __syncthreads();                           // Q staged

    bf16x8 aq[16];                             // 32q x 256k A-frags
#pragma unroll
    for (int kc = 0; kc < 16; kc++)
      aq[kc] = *(const bf16x8*)&Qs[(qq * 32 + l31) * 256 +
                                   (((kc * 2 + hi) ^ l31) << 3)];
    __syncthreads();                           // Q reads done -> bufs reusable

    f32x16 ao[4];
#pragma unroll
    for (int g = 0; g < 4; g++) ao[g] = (f32x16)(0.f);
    f32x16 al = (f32x16)(0.f);

    // stage first tile -> buf[k0&1]
    {
      const u16* Kt = Kg + (size_t)(k0 * 64) * 4096;
      const u16* Vt = Vg0 + k0 * 64;
      int bf = k0 & 1;
      if (w < 4) {
#pragma unroll
        for (int s = 0; s < 8; s++) {
          int idx = w * 8 + s;
          int kr = idx * 2 + hi;
          int klc = l31 ^ (kr & 31);
          load_lds16(Kt + (size_t)kr * 4096 + klc * 8, &Ks[bf][idx * 512]);
        }
      } else {
#pragma unroll
        for (int s = 0; s < 8; s++) {
          int idx = (w - 4) * 8 + s;
          int vr = idx * 8 + vro;
          load_lds16(Vt + (size_t)vr * 4096 + vlc * 8, &Vs[bf][idx * 512]);
        }
      }
    }

    for (int t = k0; t < k1; t++) {
      int cur = t & 1;
      __syncthreads();                         // drains tile-t stage; frees Pl

      // prefetch t+1 -> other buf; in flight across the whole tile
      if (t + 1 < k1) {
        const u16* Kt = Kg + (size_t)((t + 1) * 64) * 4096;
        const u16* Vt = Vg0 + (t + 1) * 64;
        int nb = (t + 1) & 1;
        if (w < 4) {
#pragma unroll
          for (int s = 0; s < 8; s++) {
            int idx = w * 8 + s;
            int kr = idx * 2 + hi;
            int klc = l31 ^ (kr & 31);
            load_lds16(Kt + (size_t)kr * 4096 + klc * 8, &Ks[nb][idx * 512]);
          }
        } else {
#pragma unroll
          for (int s = 0; s < 8; s++) {
            int idx = (w - 4) * 8 + s;
            int vr = idx * 8 + vro;
            load_lds16(Vt + (size_t)vr * 4096 + vlc * 8, &Vs[nb][idx * 512]);
          }
        }
      }

      // S quarter: 32q x 32k, 16 MFMA in two chains
      f32x16 se = (f32x16)(0.f);
      f32x16 so = (f32x16)(0.f);
#pragma unroll
      for (int kc = 0; kc < 8; kc++) {
        bf16x8 bk0 = *(const bf16x8*)&Ks[cur][(kh * 32 + l31) * 256 +
                                              ((((2 * kc) * 2 + hi) ^ l31) << 3)];
        se = __builtin_amdgcn_mfma_f32_32x32x16_bf16(aq[2 * kc], bk0, se, 0, 0, 0);
        bf16x8 bk1 = *(const bf16x8*)&Ks[cur][(kh * 32 + l31) * 256 +
                                              ((((2 * kc + 1) * 2 + hi) ^ l31) << 3)];
        so = __builtin_amdgcn_mfma_f32_32x32x16_bf16(aq[2 * kc + 1], bk1, so, 0, 0, 0);
      }
      f32x16 sacc = se + so;

      // softcap -> P (bf16, swizzled); mask only on diagonal tiles (t >= 2*qt)
      bool diag = (t >= 2 * qt);
#pragma unroll
      for (int reg = 0; reg < 16; reg++) {
        int qa = 4 * hi + 8 * (reg >> 2) + (reg & 3);
        int q128 = qq * 32 + qa;
        int key64 = kh * 32 + l31;
        float x = sacc[reg] * 0.00125f;          // s*(1/16)/50
        float x2 = x * x;
        float th = x * (1.f + x2 * (-0.33333333f + x2 * 0.13333333f));
        float pp = exp2f(72.134752f * (th - 1.f));  // exp(50*tanh - 50)
        if (diag && t * 64 + key64 > qt * 128 + q128) pp = 0.f;
        Pl[q128 * 64 + (((key64 >> 3) ^ (q128 & 7)) << 3) + (key64 & 7)] = f2bf(pp);
      }
      // publish P: LDS-only fence + raw barrier (prefetch vmcnt NOT drained)
      asm volatile("s_waitcnt lgkmcnt(0)" ::: "memory");
      __builtin_amdgcn_s_barrier();
      asm volatile("" ::: "memory");

      // PV: O[qq 32][dhalf 128] += P[32][64] * V[64][128]; l via ones
      bf16x8 ap[4];
#pragma unroll
      for (int kc = 0; kc < 4; kc++)
        ap[kc] = *(const bf16x8*)&Pl[(qq * 32 + l31) * 64 +
                                     (((kc * 2 + hi) ^ (l31 & 7)) << 3)];
#pragma unroll
      for (int g = 0; g < 4; g++) {
        int dd = dhalf * 128 + g * 32 + l31;
#pragma unroll
        for (int kc = 0; kc < 4; kc++) {
          bf16x8 bv = *(const bf16x8*)&Vs[cur][dd * 64 +
                                              (((kc * 2 + hi) ^ (l31 & 7)) << 3)];
          ao[g] = __builtin_amdgcn_mfma_f32_32x32x16_bf16(ap[kc], bv, ao[g], 0, 0, 0);
        }
      }
#pragma unroll
      for (int kc = 0; kc < 4; kc++)
        al = __builtin_amdgcn_mfma_f32_32x32x16_bf16(ap[kc], ones, al, 0, 0, 0);
    }

    // epilogue by mode
    if (mode == 0) {
      float inv_l[16];
#pragma unroll
      for (int reg = 0; reg < 16; reg++) inv_l[reg] = 1.f / al[reg];
      int qs = qt * 128 + qq * 32;
#pragma unroll
      for (int g = 0; g < 4; g++) {
        int col = h * 256 + dhalf * 128 + g * 32 + l31;
#pragma unroll
        for (int reg = 0; reg < 16; reg++) {
          int row = qs + 4 * hi + 8 * (reg >> 2) + (reg & 3);
          attn[(size_t)row * 2048 + col] = f2bf(ao[g][reg] * inv_l[reg]);
        }
      }
    } else {
      float* Pbuf = (mode == 1) ? PA : PB;
#pragma unroll
      for (int g = 0; g < 4; g++) {
        int col = dhalf * 128 + g * 32 + l31;
#pragma unroll
        for (int reg = 0; reg < 16; reg++) {
          int row = qq * 32 + 4 * hi + 8 * (reg >> 2) + (reg & 3);
          Pbuf[((size_t)p * 128 + row) * 256 + col] = ao[g][reg];
        }
      }
      if (dhalf == 0 && l31 == 0) {            // lanes 0 & 32 of waves 0,2,4,6
        size_t lbase = (size_t)(p * 16 + (mode - 1)) * 2048 + 1536;
#pragma unroll
        for (int reg = 0; reg < 16; reg++) {
          int row = qq * 32 + 4 * hi + 8 * (reg >> 2) + (reg & 3);
          lbuf[lbase + row] = al[reg];
        }
      }
    }
  }
}

// combine: attn rows of qt2=31-j (rows 2048..4095) = (PA+PB)/(lA+lB), bf16
__global__ __launch_bounds__(256) void combine_kernel(
    const float* __restrict__ PA, const float* __restrict__ PB,
    const float* __restrict__ lbuf, u16* __restrict__ attn) {
  int b = blockIdx.x;            // 0..255
  int p = b >> 1, half = b & 1;
  int h = p & 7, j = p >> 3;
  int qt2 = 31 - j;
  int tid = threadIdx.x;
  int row = half * 64 + (tid >> 2);   // 0..127
  int c0 = (tid & 3) * 64;
  float la = lbuf[(size_t)(p * 16) * 2048 + 1536 + row];
  float lb = lbuf[(size_t)(p * 16 + 1) * 2048 + 1536 + row];
  float inv = 1.f / (la + lb);
  size_t src = ((size_t)p * 128 + row) * 256 + c0;
  size_t dst = (size_t)(qt2 * 128 + row) * 2048 + h * 256 + c0;
#pragma unroll
  for (int c = 0; c < 64; c += 4) {
    float4 a = *(const float4*)&PA[src + c];
    float4 bb = *(const float4*)&PB[src + c];
    ushort4 o;
    o.x = f2bf((a.x + bb.x) * inv);
    o.y = f2bf((a.y + bb.y) * inv);
    o.z = f2bf((a.z + bb.z) * inv);
    o.w = f2bf((a.w + bb.w) * inv);
    *(ushort4*)&attn[dst + c] = o;
  }
}

// ---------------- launch ----------------

extern "C" void kernel_launch(void* const* d_in, const int* in_sizes, int n_in,
                              void* d_out, int out_size, void* d_ws, size_t ws_size,
                              hipStream_t stream) {
  const float* hs = (const float*)d_in[0];
  // d_in[1] attention_mask: pure causal (window 4096 never binds at S=4096)
  // d_in[2] position_ids: arange -> row index
  const float* wq = (const float*)d_in[3];
  const float* wk = (const float*)d_in[4];
  const float* wv = (const float*)d_in[5];
  const float* wo = (const float*)d_in[6];
  float* out = (float*)d_out;

  char* ws = (char*)d_ws;
  u16* hsb    = (u16*)(ws);                      // 4096x2048 bf16
  u16* wqkvT  = (u16*)(ws + 16777216);           // 4096x2048 bf16
  u16* woT    = (u16*)(ws + 33554432);           // 2048x2048 bf16
  u16* qkv    = (u16*)(ws + 41943040);           // 4096x4096 bf16
  u16* vT     = (u16*)(ws + 75497472);           // 1024x4096 bf16
  u16* attn   = (u16*)(ws + 83886080);           // 4096x2048 bf16
  // flash-phase overlays (dead regions during/after flash):
  float* PA   = (float*)(ws);                    // over hsb   (16MB, exact fit)
  float* PB   = (float*)(ws + 16777216);         // over wqkvT (16MB, exact fit)
  float* lbuf = (float*)(ws + 41943040);         // qkv base; dead V cols

  convert_hs_kernel<<<8192, 256, 0, stream>>>(hs, hsb);
  transpose_w_kernel<<<dim3(32, 32), 256, 0, stream>>>(wq, wqkvT, HIDDEN, 2048);
  transpose_w_kernel<<<dim3(16, 32), 256, 0, stream>>>(wk, wqkvT + (size_t)2048 * HIDDEN, HIDDEN, 1024);
  transpose_w_kernel<<<dim3(16, 32), 256, 0, stream>>>(wv, wqkvT + (size_t)3072 * HIDDEN, HIDDEN, 1024);
  transpose_w_kernel<<<dim3(32, 32), 256, 0, stream>>>(wo, woT, HIDDEN, 2048);

  gemm256_kernel<<<dim3(16, 16), 512, 0, stream>>>(hsb, wqkvT, qkv, 4096, 4096, 2048);
  rope_kernel<<<2048, 256, 0, stream>>>(qkv);
  transpose_v_kernel<<<dim3(16, 64), 256, 0, stream>>>(qkv, vT);

  flash_kernel<<<256, 512, 0, stream>>>(qkv, vT, attn, PA, PB, lbuf);
  combine_kernel<<<256, 256, 0, stream>>>(PA, PB, lbuf, attn);
  gemm_bf16_kernel<true><<<dim3(16, 32), 256, 0, stream>>>(attn, woT, out, 4096, 2048, 2048);
}

// Round 7
// 451.598 us; speedup vs baseline: 1.1666x; 1.1666x over previous
//
#include <hip/hip_runtime.h>

// Gemma2 attention, S=4096 HID=2048 NH=8 NKV=4 HD=256, causal, tanh softcap 50,
// scaling 1/16. R12: consolidation. R11's single 8-wave block regressed flash
// (235us, MfmaUtil 13.9): one barrier domain kills the cross-block phase
// diversity that let R9's two independent 4-wave blocks overlap staging with
// compute (m114). Revert flash to R9 (166-172us measured), keep the two
// independently-validated wins: gemm256 for gemm1 (-13us, R10 A/B) and the
// one-sincos-per-(s,i) rope (R11). Flash: 2 blocks/CU, balanced 32/33-tile
// k-split with additive partials, combine kernel.

#define SEQ 4096
#define HIDDEN 2048
#define NHEADS 8
#define HDIM 256

typedef unsigned short u16;
typedef __attribute__((ext_vector_type(8))) __bf16 bf16x8;
typedef __attribute__((ext_vector_type(4))) float f32x4;
typedef __attribute__((ext_vector_type(16))) float f32x16;

static __device__ inline u16 f2bf(float f) {
  union { float f; unsigned u; } x; x.f = f;
  unsigned r = x.u + 0x7FFFu + ((x.u >> 16) & 1u);   // RNE
  return (u16)(r >> 16);
}
static __device__ inline float bf2f(u16 u) {
  union { unsigned u; float f; } x; x.u = ((unsigned)u) << 16;
  return x.f;
}

typedef __attribute__((address_space(1))) const unsigned int* gp_t;
typedef __attribute__((address_space(3))) unsigned int* lp_t;
static __device__ inline void load_lds16(const u16* g, u16* l) {
  __builtin_amdgcn_global_load_lds((gp_t)g, (lp_t)l, 16, 0, 0);
}

#define BARX() do { __builtin_amdgcn_s_barrier(); asm volatile("" ::: "memory"); } while (0)

// ---------------- prep kernels ----------------

__global__ void convert_hs_kernel(const float* __restrict__ src, u16* __restrict__ dst) {
  int i = blockIdx.x * 256 + threadIdx.x;
  float4 v = ((const float4*)src)[i];
  ushort4 o;
  o.x = f2bf(v.x); o.y = f2bf(v.y); o.z = f2bf(v.z); o.w = f2bf(v.w);
  ((ushort4*)dst)[i] = o;
}

// src fp32 (K x N) -> dst bf16 (N x K), dst row stride = K (HIDDEN)
__global__ void transpose_w_kernel(const float* __restrict__ src, u16* __restrict__ dst,
                                   int K, int N) {
  __shared__ u16 tile[64][65];
  int n0 = blockIdx.x * 64, k0 = blockIdx.y * 64;
  int tid = threadIdx.x;
  for (int i = 0; i < 16; i++) {
    int idx = i * 256 + tid; int r = idx >> 6, c = idx & 63;
    tile[r][c] = f2bf(src[(size_t)(k0 + r) * N + n0 + c]);
  }
  __syncthreads();
  for (int i = 0; i < 16; i++) {
    int idx = i * 256 + tid; int r = idx >> 6, c = idx & 63;
    dst[(size_t)(n0 + r) * K + k0 + c] = tile[c][r];
  }
}

// RoPE in place on qkv[4096][4096]: q cols 0..2047, k cols 2048..3071.
// One sincos per (s,i); loop the 12 q/k "heads" (12x fewer transcendentals).
__global__ void rope_kernel(u16* qkv) {
  int idx = blockIdx.x * 256 + threadIdx.x;        // 4096*128
  int s = idx >> 7;
  int i = idx & 127;
  float inv = __expf(-(float)i * 0.0719557841560639f);  // ln(10000)/128
  float ang = (float)s * inv;
  float sn, cs;
  sincosf(ang, &sn, &cs);
  size_t rowb = (size_t)s * 4096;
#pragma unroll
  for (int hh = 0; hh < 12; hh++) {
    size_t base = rowb + hh * 256 + i;
    float a = bf2f(qkv[base]);
    float b = bf2f(qkv[base + 128]);
    qkv[base]       = f2bf(a * cs - b * sn);
    qkv[base + 128] = f2bf(b * cs + a * sn);
  }
}

// qkv v-part (rows s, cols 3072+d), d in 0..1023 -> vT[d][s]
__global__ void transpose_v_kernel(const u16* __restrict__ qkv, u16* __restrict__ vT) {
  __shared__ u16 tile[64][65];
  int d0 = blockIdx.x * 64, s0 = blockIdx.y * 64;
  int tid = threadIdx.x;
  for (int i = 0; i < 16; i++) {
    int idx = i * 256 + tid; int r = idx >> 6, c = idx & 63;
    tile[r][c] = qkv[(size_t)(s0 + r) * 4096 + 3072 + d0 + c];
  }
  __syncthreads();
  for (int i = 0; i < 16; i++) {
    int idx = i * 256 + tid; int r = idx >> 6, c = idx & 63;
    vT[(size_t)(d0 + r) * 4096 + s0 + c] = tile[c][r];
  }
}

// ---------------- GEMM 256^2, BK=32, ring-4, counted vmcnt (gemm1) ----------------

__global__ __launch_bounds__(512, 2) void gemm256_kernel(
    const u16* __restrict__ A, const u16* __restrict__ Bt, u16* __restrict__ C,
    int M, int N, int K) {
  __shared__ __attribute__((aligned(16))) u16 lds[4][2][256 * 32];
  int tid = threadIdx.x;
  int wid = tid >> 6, lane = tid & 63;
  int lm = lane & 15, kq = lane >> 4;
  int wm = (wid >> 2) * 128, wn = (wid & 3) * 64;
  int m0 = blockIdx.y * 256, n0 = blockIdx.x * 256;
  int T = K >> 5;

  int idx0 = tid, idx1 = 512 + tid;
  int r0 = idx0 >> 2, c0 = idx0 & 3;
  int r1 = idx1 >> 2, c1 = idx1 & 3;
  const u16* gA0 = A  + (size_t)(m0 + r0) * K + ((c0 ^ (r0 & 3)) << 3);
  const u16* gA1 = A  + (size_t)(m0 + r1) * K + ((c1 ^ (r1 & 3)) << 3);
  const u16* gB0 = Bt + (size_t)(n0 + r0) * K + ((c0 ^ (r0 & 3)) << 3);
  const u16* gB1 = Bt + (size_t)(n0 + r1) * K + ((c1 ^ (r1 & 3)) << 3);

  f32x4 acc[8][4];
#pragma unroll
  for (int a = 0; a < 8; a++)
#pragma unroll
    for (int b = 0; b < 4; b++) acc[a][b] = (f32x4){0.f, 0.f, 0.f, 0.f};

  int xsw = ((kq ^ (lm & 3)) << 3);

#pragma unroll
  for (int t = 0; t < 2; t++) {
    int s = t & 3;
    load_lds16(gA0 + t * 32, &lds[s][0][idx0 * 8]);
    load_lds16(gA1 + t * 32, &lds[s][0][idx1 * 8]);
    load_lds16(gB0 + t * 32, &lds[s][1][idx0 * 8]);
    load_lds16(gB1 + t * 32, &lds[s][1][idx1 * 8]);
  }
  asm volatile("s_waitcnt vmcnt(4)" ::: "memory");
  BARX();

  for (int t = 0; t < T; ++t) {
    const u16* As = &lds[t & 3][0][0];
    const u16* Bs = &lds[t & 3][1][0];
    int sn = (t + 2) & 3;
    bool st = (t + 2) < T;

    bf16x8 a0[4], bb[4];
#pragma unroll
    for (int f = 0; f < 4; f++)
      a0[f] = *(const bf16x8*)&As[(wm + f * 16 + lm) * 32 + xsw];
#pragma unroll
    for (int f = 0; f < 4; f++)
      bb[f] = *(const bf16x8*)&Bs[(wn + f * 16 + lm) * 32 + xsw];
    if (st) {
      load_lds16(gA0 + (t + 2) * 32, &lds[sn][0][idx0 * 8]);
      load_lds16(gA1 + (t + 2) * 32, &lds[sn][0][idx1 * 8]);
    }
    BARX();
    __builtin_amdgcn_s_setprio(1);
#pragma unroll
    for (int mi = 0; mi < 4; mi++)
#pragma unroll
      for (int ni = 0; ni < 4; ni++)
        acc[mi][ni] = __builtin_amdgcn_mfma_f32_16x16x32_bf16(a0[mi], bb[ni],
                                                             acc[mi][ni], 0, 0, 0);
    __builtin_amdgcn_s_setprio(0);

    bf16x8 a1[4];
#pragma unroll
    for (int f = 0; f < 4; f++)
      a1[f] = *(const bf16x8*)&As[(wm + 64 + f * 16 + lm) * 32 + xsw];
    if (st) {
      load_lds16(gB0 + (t + 2) * 32, &lds[sn][1][idx0 * 8]);
      load_lds16(gB1 + (t + 2) * 32, &lds[sn][1][idx1 * 8]);
    }
    BARX();
    __builtin_amdgcn_s_setprio(1);
#pragma unroll
    for (int mi = 0; mi < 4; mi++)
#pragma unroll
      for (int ni = 0; ni < 4; ni++)
        acc[4 + mi][ni] = __builtin_amdgcn_mfma_f32_16x16x32_bf16(a1[mi], bb[ni],
                                                                 acc[4 + mi][ni], 0, 0, 0);
    __builtin_amdgcn_s_setprio(0);

    if (t < T - 1) {
      if (st) asm volatile("s_waitcnt vmcnt(4)" ::: "memory");
      else    asm volatile("s_waitcnt vmcnt(0)" ::: "memory");
      BARX();
    }
  }

#pragma unroll
  for (int mi = 0; mi < 8; mi++) {
    int row = m0 + wm + mi * 16 + kq * 4;
#pragma unroll
    for (int ni = 0; ni < 4; ni++) {
      int col = n0 + wn + ni * 16 + lm;
#pragma unroll
      for (int r = 0; r < 4; r++)
        C[(size_t)(row + r) * N + col] = f2bf(acc[mi][ni][r]);
    }
  }
}

// ---------------- GEMM (m97 structure): C = A(MxK) * Bt(NxK)^T ----------------

template <bool OUT_F32>
__global__ __launch_bounds__(256, 2) void gemm_bf16_kernel(
    const u16* __restrict__ A, const u16* __restrict__ Bt, void* __restrict__ Cout,
    int M, int N, int K) {
  __shared__ __attribute__((aligned(16))) u16 As[128 * 64];
  __shared__ __attribute__((aligned(16))) u16 Bs[128 * 64];
  int tid = threadIdx.x;
  int wave = tid >> 6, lane = tid & 63;
  int lm = lane & 15, qd = lane >> 4;
  int m0 = blockIdx.y * 128, n0 = blockIdx.x * 128;
  int wm = (wave >> 1) * 64, wn = (wave & 1) * 64;

  f32x4 acc[4][4];
#pragma unroll
  for (int a = 0; a < 4; a++)
#pragma unroll
    for (int b = 0; b < 4; b++) acc[a][b] = (f32x4){0.f, 0.f, 0.f, 0.f};

  int srow = lane >> 3;
  int scol = (lane & 7) * 8;

  for (int kt = 0; kt < K; kt += 64) {
    __syncthreads();
#pragma unroll
    for (int t = 0; t < 4; t++) {
      int j = wave * 4 + t;
      int row = j * 8 + srow;
      load_lds16(A  + (size_t)(m0 + row) * K + kt + scol, As + j * 512);
      load_lds16(Bt + (size_t)(n0 + row) * K + kt + scol, Bs + j * 512);
    }
    __syncthreads();
#pragma unroll
    for (int kk = 0; kk < 2; kk++) {
      bf16x8 af[4], bfr[4];
#pragma unroll
      for (int mi = 0; mi < 4; mi++)
        af[mi] = *(const bf16x8*)&As[(wm + mi * 16 + lm) * 64 + kk * 32 + qd * 8];
#pragma unroll
      for (int ni = 0; ni < 4; ni++)
        bfr[ni] = *(const bf16x8*)&Bs[(wn + ni * 16 + lm) * 64 + kk * 32 + qd * 8];
#pragma unroll
      for (int mi = 0; mi < 4; mi++)
#pragma unroll
        for (int ni = 0; ni < 4; ni++)
          acc[mi][ni] = __builtin_amdgcn_mfma_f32_16x16x32_bf16(af[mi], bfr[ni],
                                                               acc[mi][ni], 0, 0, 0);
    }
  }
#pragma unroll
  for (int mi = 0; mi < 4; mi++) {
    int row = m0 + wm + mi * 16 + qd * 4;
#pragma unroll
    for (int ni = 0; ni < 4; ni++) {
      int col = n0 + wn + ni * 16 + lm;
#pragma unroll
      for (int r = 0; r < 4; r++) {
        float v = acc[mi][ni][r];
        if (OUT_F32) ((float*)Cout)[(size_t)(row + r) * N + col] = v;
        else         ((u16*)Cout)[(size_t)(row + r) * N + col] = f2bf(v);
      }
    }
  }
}

// ---------------- flash attention, balanced 2 blocks/CU (R9) ----------------
// l partial slots: dead V-quarter of qkv. Pair r: lA at row r*16, lB at row
// r*16+1, float offset row*2048 + 1536 (byte 6144 within the 8KB row).

__global__ __launch_bounds__(256, 2) void flash_kernel(
    const u16* __restrict__ qkv, const u16* __restrict__ vT,
    u16* __restrict__ attn, float* __restrict__ PA, float* __restrict__ PB,
    float* __restrict__ lbuf /* == (float*)qkv base */) {
  __shared__ __attribute__((aligned(16))) u16 Ks[64 * 256];
  __shared__ __attribute__((aligned(16))) u16 Vs[256 * 64];
  __shared__ __attribute__((aligned(16))) u16 Pl[64 * 64];

  int tid = threadIdx.x;
  int w = tid >> 6, lane = tid & 63;
  int l31 = lane & 31, hi = lane >> 5;
  int qhalf = w >> 1, kh = w & 1, dhalf = w & 1;

  int b = blockIdx.x;            // 0..511
  int r = b & 255;
  int h = r & 7;                 // one head per XCD; same for b and b+256
  int pi = r >> 3;               // 0..31
  int kvh = h >> 1;
  int isA = (b < 256);
  int nseg = isA ? 2 : 1;

  int vlc = (lane & 7) ^ ((lane >> 3) & 7);    // V logical 16B chunk
  int vro = lane >> 3;                          // V row offset in 8-row window

  const u16* Kg  = qkv + 2048 + (size_t)kvh * 256;
  const u16* Vg0 = vT + (size_t)(kvh * 256) * 4096;

  bf16x8 ones;
#pragma unroll
  for (int e = 0; e < 8; e++) ones[e] = (__bf16)1.0f;

  for (int si = 0; si < nseg; si++) {
    int qt, k0, k1, mode;                      // mode: 0 owned, 1 ->PA, 2 ->PB
    if (isA && si == 0) { qt = pi;      k0 = 0;       k1 = pi + 1;  mode = 0; }
    else if (isA)       { qt = 63 - pi; k0 = 0;       k1 = 31 - pi; mode = 1; }
    else                { qt = 63 - pi; k0 = 31 - pi; k1 = 64 - pi; mode = 2; }

    // stage Q (64x256) -> Ks
    {
      const u16* Qg = qkv + (size_t)(qt * 64) * 4096 + h * 256;
#pragma unroll
      for (int s = 0; s < 8; s++) {
        int kr = (w * 8 + s) * 2 + hi;
        int klc = l31 ^ (kr & 31);
        load_lds16(Qg + (size_t)kr * 4096 + klc * 8, &Ks[(w * 8 + s) * 512]);
      }
    }
    __syncthreads();                           // Q staged

    bf16x8 aq[16];                             // 32q x 256k A-frags
#pragma unroll
    for (int kc = 0; kc < 16; kc++)
      aq[kc] = *(const bf16x8*)&Ks[(qhalf * 32 + l31) * 256 +
                                   (((kc * 2 + hi) ^ l31) << 3)];
    __syncthreads();                           // aq reads done -> Ks reusable

    f32x16 ao[4];
#pragma unroll
    for (int g = 0; g < 4; g++) ao[g] = (f32x16)(0.f);
    f32x16 al = (f32x16)(0.f);

    for (int t = k0; t < k1; t++) {
      // stage K,V tile t (buffers free: trailing barrier)
      {
        const u16* Kt = Kg + (size_t)(t * 64) * 4096;
        const u16* Vt = Vg0 + t * 64;
#pragma unroll
        for (int s = 0; s < 8; s++) {
          int kr = (w * 8 + s) * 2 + hi;
          int klc = l31 ^ (kr & 31);
          load_lds16(Kt + (size_t)kr * 4096 + klc * 8, &Ks[(w * 8 + s) * 512]);
          int vr = (w * 8 + s) * 8 + vro;
          load_lds16(Vt + (size_t)vr * 4096 + vlc * 8, &Vs[(w * 8 + s) * 512]);
        }
      }
      __syncthreads();                         // drain + rendezvous: K,V staged

      // S quarter: 32q x 32k, 16 MFMA in TWO independent chains (ILP 2)
      f32x16 se = (f32x16)(0.f);
      f32x16 so = (f32x16)(0.f);
#pragma unroll
      for (int kc = 0; kc < 8; kc++) {
        bf16x8 bk0 = *(const bf16x8*)&Ks[(kh * 32 + l31) * 256 +
                                         ((((2 * kc) * 2 + hi) ^ l31) << 3)];
        se = __builtin_amdgcn_mfma_f32_32x32x16_bf16(aq[2 * kc], bk0, se, 0, 0, 0);
        bf16x8 bk1 = *(const bf16x8*)&Ks[(kh * 32 + l31) * 256 +
                                         ((((2 * kc + 1) * 2 + hi) ^ l31) << 3)];
        so = __builtin_amdgcn_mfma_f32_32x32x16_bf16(aq[2 * kc + 1], bk1, so, 0, 0, 0);
      }
      f32x16 sacc = se + so;

      // softcap -> P (bf16, swizzled shared LDS); mask only on diagonal tile
      bool diag = (t == qt);
#pragma unroll
      for (int reg = 0; reg < 16; reg++) {
        int qa = 4 * hi + 8 * (reg >> 2) + (reg & 3);   // local q in 0..31
        int q64 = qhalf * 32 + qa;
        int key64 = kh * 32 + l31;
        float x = sacc[reg] * 0.00125f;          // s*(1/16)/50
        float x2 = x * x;
        float th = x * (1.f + x2 * (-0.33333333f + x2 * 0.13333333f));
        float p = exp2f(72.134752f * (th - 1.f));  // exp(50*tanh - 50)
        if (diag && key64 > q64) p = 0.f;
        Pl[q64 * 64 + (((key64 >> 3) ^ (q64 & 7)) << 3) + (key64 & 7)] = f2bf(p);
      }
      __syncthreads();                         // publish P

      // PV: O[qhalf 32][dhalf 128] += P[32][64] * V[64][128]; l via ones
      bf16x8 ap[4];
#pragma unroll
      for (int kc = 0; kc < 4; kc++)
        ap[kc] = *(const bf16x8*)&Pl[(qhalf * 32 + l31) * 64 +
                                     (((kc * 2 + hi) ^ (l31 & 7)) << 3)];
#pragma unroll
      for (int g = 0; g < 4; g++) {
        int dd = dhalf * 128 + g * 32 + l31;
#pragma unroll
        for (int kc = 0; kc < 4; kc++) {
          bf16x8 bv = *(const bf16x8*)&Vs[dd * 64 +
                                          (((kc * 2 + hi) ^ (l31 & 7)) << 3)];
          ao[g] = __builtin_amdgcn_mfma_f32_32x32x16_bf16(ap[kc], bv, ao[g], 0, 0, 0);
        }
      }
#pragma unroll
      for (int kc = 0; kc < 4; kc++)
        al = __builtin_amdgcn_mfma_f32_32x32x16_bf16(ap[kc], ones, al, 0, 0, 0);

      __syncthreads();                         // all readers done -> buffers free
    }

    // epilogue by mode
    if (mode == 0) {
      // owned: normalize + store bf16
      float inv_l[16];
#pragma unroll
      for (int reg = 0; reg < 16; reg++) inv_l[reg] = 1.f / al[reg];
      int qs = qt * 64 + qhalf * 32;
#pragma unroll
      for (int g = 0; g < 4; g++) {
        int col = h * 256 + dhalf * 128 + g * 32 + l31;
#pragma unroll
        for (int reg = 0; reg < 16; reg++) {
          int row = qs + 4 * hi + 8 * (reg >> 2) + (reg & 3);
          attn[(size_t)row * 2048 + col] = f2bf(ao[g][reg] * inv_l[reg]);
        }
      }
    } else {
      // partial: f32 O -> PA/PB[r][64][256]; l -> dead-V slot of qkv
      float* Pbuf = (mode == 1) ? PA : PB;
#pragma unroll
      for (int g = 0; g < 4; g++) {
        int col = dhalf * 128 + g * 32 + l31;
#pragma unroll
        for (int reg = 0; reg < 16; reg++) {
          int row = qhalf * 32 + 4 * hi + 8 * (reg >> 2) + (reg & 3);
          Pbuf[((size_t)r * 64 + row) * 256 + col] = ao[g][reg];
        }
      }
      if (dhalf == 0 && l31 == 0) {            // lanes 0 & 32 of waves 0,2
        size_t lbase = (size_t)(r * 16 + (mode - 1)) * 2048 + 1536;
#pragma unroll
        for (int reg = 0; reg < 16; reg++) {
          int row = qhalf * 32 + 4 * hi + 8 * (reg >> 2) + (reg & 3);
          lbuf[lbase + row] = al[reg];
        }
      }
    }
  }
}

// combine: attn rows of qt2=63-pi (rows 2048..4095) = (PA+PB)/(lA+lB), bf16
__global__ __launch_bounds__(256) void combine_kernel(
    const float* __restrict__ PA, const float* __restrict__ PB,
    const float* __restrict__ lbuf, u16* __restrict__ attn) {
  int p = blockIdx.x;            // pair 0..255
  int h = p & 7, pi = p >> 3;
  int qt2 = 63 - pi;
  int tid = threadIdx.x;
  int row = tid >> 2;            // 0..63
  int c0 = (tid & 3) * 64;
  float la = lbuf[(size_t)(p * 16) * 2048 + 1536 + row];
  float lb = lbuf[(size_t)(p * 16 + 1) * 2048 + 1536 + row];
  float inv = 1.f / (la + lb);
  size_t src = ((size_t)p * 64 + row) * 256 + c0;
  size_t dst = (size_t)(qt2 * 64 + row) * 2048 + h * 256 + c0;
#pragma unroll
  for (int c = 0; c < 64; c += 4) {
    float4 a = *(const float4*)&PA[src + c];
    float4 bb = *(const float4*)&PB[src + c];
    ushort4 o;
    o.x = f2bf((a.x + bb.x) * inv);
    o.y = f2bf((a.y + bb.y) * inv);
    o.z = f2bf((a.z + bb.z) * inv);
    o.w = f2bf((a.w + bb.w) * inv);
    *(ushort4*)&attn[dst + c] = o;
  }
}

// ---------------- launch ----------------

extern "C" void kernel_launch(void* const* d_in, const int* in_sizes, int n_in,
                              void* d_out, int out_size, void* d_ws, size_t ws_size,
                              hipStream_t stream) {
  const float* hs = (const float*)d_in[0];
  // d_in[1] attention_mask: pure causal (window 4096 never binds at S=4096)
  // d_in[2] position_ids: arange -> row index
  const float* wq = (const float*)d_in[3];
  const float* wk = (const float*)d_in[4];
  const float* wv = (const float*)d_in[5];
  const float* wo = (const float*)d_in[6];
  float* out = (float*)d_out;

  char* ws = (char*)d_ws;
  u16* hsb    = (u16*)(ws);                      // 4096x2048 bf16
  u16* wqkvT  = (u16*)(ws + 16777216);           // 4096x2048 bf16
  u16* woT    = (u16*)(ws + 33554432);           // 2048x2048 bf16
  u16* qkv    = (u16*)(ws + 41943040);           // 4096x4096 bf16
  u16* vT     = (u16*)(ws + 75497472);           // 1024x4096 bf16
  u16* attn   = (u16*)(ws + 83886080);           // 4096x2048 bf16
  // flash-phase overlays (dead regions during/after flash):
  float* PA   = (float*)(ws);                    // over hsb   (16MB)
  float* PB   = (float*)(ws + 16777216);         // over wqkvT (16MB)
  float* lbuf = (float*)(ws + 41943040);         // qkv base; dead V cols

  convert_hs_kernel<<<8192, 256, 0, stream>>>(hs, hsb);
  transpose_w_kernel<<<dim3(32, 32), 256, 0, stream>>>(wq, wqkvT, HIDDEN, 2048);
  transpose_w_kernel<<<dim3(16, 32), 256, 0, stream>>>(wk, wqkvT + (size_t)2048 * HIDDEN, HIDDEN, 1024);
  transpose_w_kernel<<<dim3(16, 32), 256, 0, stream>>>(wv, wqkvT + (size_t)3072 * HIDDEN, HIDDEN, 1024);
  transpose_w_kernel<<<dim3(32, 32), 256, 0, stream>>>(wo, woT, HIDDEN, 2048);

  gemm256_kernel<<<dim3(16, 16), 512, 0, stream>>>(hsb, wqkvT, qkv, 4096, 4096, 2048);
  rope_kernel<<<2048, 256, 0, stream>>>(qkv);
  transpose_v_kernel<<<dim3(16, 64), 256, 0, stream>>>(qkv, vT);

  flash_kernel<<<512, 256, 0, stream>>>(qkv, vT, attn, PA, PB, lbuf);
  combine_kernel<<<256, 256, 0, stream>>>(PA, PB, lbuf, attn);
  gemm_bf16_kernel<true><<<dim3(16, 32), 256, 0, stream>>>(attn, woT, out, 4096, 2048, 2048);
}